// Round 1
// baseline (636.934 us; speedup 1.0000x reference)
//
#include <hip/hip_runtime.h>

#define EMBED 128
#define ATTR  25
#define REM   28
#define NL 50
#define NT 2
#define NF 2
#define NE 3
#define NP 20
#define CROWS 77   // 50 + 2 + 2 + 3 + 20 projected rows

// Kernel 1: precompute projected tables C[77][128].
// Row layout: [0,50) level, [50,52) type, [52,54) feature, [54,57) exchange (+b folded), [57,77) pair.
__global__ __launch_bounds__(EMBED) void precompute_C(
    const float* __restrict__ level_tab,
    const float* __restrict__ type_tab,
    const float* __restrict__ feature_tab,
    const float* __restrict__ exchange_tab,
    const float* __restrict__ pair_tab,
    const float* __restrict__ W,      // [128][128] row-major, y = x @ W^T -> y[e] = sum_f x[f] W[e][f]
    const float* __restrict__ b,
    float* __restrict__ C)            // [77][128]
{
    const int r = blockIdx.x;    // 0..76
    const int e = threadIdx.x;   // 0..127
    const float* tab;
    int off, len;
    float acc = 0.0f;
    if (r < NL)                { tab = level_tab    + r * ATTR;        off = 0;   len = ATTR; }
    else if (r < NL + NT)      { tab = type_tab     + (r - 50) * ATTR; off = 25;  len = ATTR; }
    else if (r < NL + NT + NF) { tab = feature_tab  + (r - 52) * ATTR; off = 50;  len = ATTR; }
    else if (r < 57)           { tab = exchange_tab + (r - 54) * ATTR; off = 75;  len = ATTR; acc = b[e]; }
    else                       { tab = pair_tab     + (r - 57) * REM;  off = 100; len = REM;  }

    const float* w = W + (size_t)e * EMBED + off;
    #pragma unroll 4
    for (int f = 0; f < len; ++f) acc = fmaf(w[f], tab[f], acc);
    C[r * EMBED + e] = acc;
}

// Kernel 2: out[n] = C_level[li[n]] + C_type[ti[n]] + C_feat[fi[n]] + C_exch[ei[n]] + C_pair[pi[n]]
// 32 lanes per row, each lane owns one float4 column chunk. C staged in LDS (39424 B).
__global__ __launch_bounds__(256) void gather_add(
    const int* __restrict__ li, const int* __restrict__ ti,
    const int* __restrict__ fi, const int* __restrict__ ei,
    const int* __restrict__ pi,
    const float* __restrict__ C,
    float* __restrict__ out, int N)
{
    __shared__ float4 sC[CROWS * 32];   // 77 rows x 32 float4 = 39424 B
    const float4* C4 = (const float4*)C;
    for (int i = threadIdx.x; i < CROWS * 32; i += 256) sC[i] = C4[i];
    __syncthreads();

    const int c   = threadIdx.x & 31;   // float4 chunk within the row
    const int rib = threadIdx.x >> 5;   // row-in-block 0..7
    const int stride = gridDim.x * 8;

    for (int n = blockIdx.x * 8 + rib; n < N; n += stride) {
        const int l = li[n];
        const int t = ti[n];
        const int f = fi[n];
        const int e = ei[n];
        const int p = pi[n];

        float4 a0 = sC[l * 32 + c];
        float4 a1 = sC[(50 + t) * 32 + c];
        float4 a2 = sC[(52 + f) * 32 + c];
        float4 a3 = sC[(54 + e) * 32 + c];
        float4 a4 = sC[(57 + p) * 32 + c];

        float4 r;
        r.x = a0.x + a1.x + a2.x + a3.x + a4.x;
        r.y = a0.y + a1.y + a2.y + a3.y + a4.y;
        r.z = a0.z + a1.z + a2.z + a3.z + a4.z;
        r.w = a0.w + a1.w + a2.w + a3.w + a4.w;

        ((float4*)(out + (size_t)n * EMBED))[c] = r;
    }
}

extern "C" void kernel_launch(void* const* d_in, const int* in_sizes, int n_in,
                              void* d_out, int out_size, void* d_ws, size_t ws_size,
                              hipStream_t stream) {
    const float* level_tab    = (const float*)d_in[0];
    const float* type_tab     = (const float*)d_in[1];
    const float* feature_tab  = (const float*)d_in[2];
    const float* exchange_tab = (const float*)d_in[3];
    const float* pair_tab     = (const float*)d_in[4];
    const float* W            = (const float*)d_in[5];
    const float* b            = (const float*)d_in[6];
    const int*   li           = (const int*)d_in[7];
    const int*   ti           = (const int*)d_in[8];
    const int*   fi           = (const int*)d_in[9];
    const int*   ei           = (const int*)d_in[10];
    const int*   pi           = (const int*)d_in[11];

    float* out = (float*)d_out;
    float* C   = (float*)d_ws;          // 77*128*4 = 39424 bytes of scratch

    const int N = in_sizes[7];          // 1048576

    precompute_C<<<CROWS, EMBED, 0, stream>>>(
        level_tab, type_tab, feature_tab, exchange_tab, pair_tab, W, b, C);

    const int blocks = 2048;            // 8 rows per block-iteration, grid-stride
    gather_add<<<blocks, 256, 0, stream>>>(li, ti, fi, ei, pi, C, out, N);
}

// Round 2
// 592.148 us; speedup vs baseline: 1.0756x; 1.0756x over previous
//
#include <hip/hip_runtime.h>

#define EMBED 128
#define ATTR  25
#define REM   28
#define NL 50
#define NTFE 12            // type(2) x feature(2) x exchange(3) combos
#define NP 20
#define CROWS (NL + NTFE + NP)   // 82 rows
#define ROW_TFE NL               // 50
#define ROW_PAIR (NL + NTFE)     // 62

// Kernel 1: precompute projected tables C[82][128].
// rows [0,50):  W[:,0:25]   @ level_tab[r]
// rows [50,62): W[:,25:50]  @ type_tab[t] + W[:,50:75] @ feature_tab[f]
//               + W[:,75:100] @ exchange_tab[e] + b,  q = t*6 + f*3 + e
// rows [62,82): W[:,100:128] @ pair_tab[p]
__global__ __launch_bounds__(EMBED) void precompute_C(
    const float* __restrict__ level_tab,
    const float* __restrict__ type_tab,
    const float* __restrict__ feature_tab,
    const float* __restrict__ exchange_tab,
    const float* __restrict__ pair_tab,
    const float* __restrict__ W,      // [128][128] row-major; y[e] = sum_f x[f] * W[e][f]
    const float* __restrict__ b,
    float* __restrict__ C)            // [82][128]
{
    const int r = blockIdx.x;    // 0..81
    const int e = threadIdx.x;   // 0..127
    const float* w = W + (size_t)e * EMBED;
    float acc = 0.0f;

    if (r < NL) {
        const float* tab = level_tab + r * ATTR;
        #pragma unroll
        for (int k = 0; k < ATTR; ++k) acc = fmaf(w[k], tab[k], acc);
    } else if (r < ROW_PAIR) {
        const int q = r - ROW_TFE;           // 0..11
        const int t = q / 6;
        const int f = (q % 6) / 3;
        const int ex = q % 3;
        const float* tt = type_tab     + t  * ATTR;
        const float* ft = feature_tab  + f  * ATTR;
        const float* et = exchange_tab + ex * ATTR;
        acc = b[e];
        #pragma unroll
        for (int k = 0; k < ATTR; ++k) {
            acc = fmaf(w[25 + k], tt[k], acc);
            acc = fmaf(w[50 + k], ft[k], acc);
            acc = fmaf(w[75 + k], et[k], acc);
        }
    } else {
        const float* pt = pair_tab + (r - ROW_PAIR) * REM;
        #pragma unroll
        for (int k = 0; k < REM; ++k) acc = fmaf(w[100 + k], pt[k], acc);
    }
    C[r * EMBED + e] = acc;
}

// Kernel 2: out[n] = C_lvl[l[n]] + C_tfe[t*6+f*3+e] + C_pair[p[n]]
// Half-wave (32 lanes) handles 4 consecutive rows per iteration; indices via int4.
__global__ __launch_bounds__(512) void gather_add(
    const int* __restrict__ li, const int* __restrict__ ti,
    const int* __restrict__ fi, const int* __restrict__ ei,
    const int* __restrict__ pi,
    const float* __restrict__ C,
    float* __restrict__ out, int N4)     // N4 = N/4
{
    __shared__ float4 sC[CROWS * 32];    // 82 rows x 512 B = 41984 B
    const float4* C4 = (const float4*)C;
    for (int i = threadIdx.x; i < CROWS * 32; i += 512) sC[i] = C4[i];
    __syncthreads();

    const int c  = threadIdx.x & 31;     // float4 chunk within a row
    const int hw = threadIdx.x >> 5;     // half-wave id 0..15
    const int stride = gridDim.x * 16;

    for (int g = blockIdx.x * 16 + hw; g < N4; g += stride) {
        const int n0 = g * 4;
        int4 l4 = *(const int4*)(li + n0);
        int4 t4 = *(const int4*)(ti + n0);
        int4 f4 = *(const int4*)(fi + n0);
        int4 e4 = *(const int4*)(ei + n0);
        int4 p4 = *(const int4*)(pi + n0);

        const int q0 = ROW_TFE + t4.x * 6 + f4.x * 3 + e4.x;
        const int q1 = ROW_TFE + t4.y * 6 + f4.y * 3 + e4.y;
        const int q2 = ROW_TFE + t4.z * 6 + f4.z * 3 + e4.z;
        const int q3 = ROW_TFE + t4.w * 6 + f4.w * 3 + e4.w;

        float4 a0 = sC[l4.x * 32 + c], b0 = sC[q0 * 32 + c], d0 = sC[(ROW_PAIR + p4.x) * 32 + c];
        float4 a1 = sC[l4.y * 32 + c], b1 = sC[q1 * 32 + c], d1 = sC[(ROW_PAIR + p4.y) * 32 + c];
        float4 a2 = sC[l4.z * 32 + c], b2 = sC[q2 * 32 + c], d2 = sC[(ROW_PAIR + p4.z) * 32 + c];
        float4 a3 = sC[l4.w * 32 + c], b3 = sC[q3 * 32 + c], d3 = sC[(ROW_PAIR + p4.w) * 32 + c];

        float4 r0, r1, r2, r3;
        r0.x = a0.x + b0.x + d0.x; r0.y = a0.y + b0.y + d0.y; r0.z = a0.z + b0.z + d0.z; r0.w = a0.w + b0.w + d0.w;
        r1.x = a1.x + b1.x + d1.x; r1.y = a1.y + b1.y + d1.y; r1.z = a1.z + b1.z + d1.z; r1.w = a1.w + b1.w + d1.w;
        r2.x = a2.x + b2.x + d2.x; r2.y = a2.y + b2.y + d2.y; r2.z = a2.z + b2.z + d2.z; r2.w = a2.w + b2.w + d2.w;
        r3.x = a3.x + b3.x + d3.x; r3.y = a3.y + b3.y + d3.y; r3.z = a3.z + b3.z + d3.z; r3.w = a3.w + b3.w + d3.w;

        float4* o = (float4*)(out + (size_t)n0 * EMBED) + c;
        o[0]  = r0;
        o[32] = r1;
        o[64] = r2;
        o[96] = r3;
    }
}

extern "C" void kernel_launch(void* const* d_in, const int* in_sizes, int n_in,
                              void* d_out, int out_size, void* d_ws, size_t ws_size,
                              hipStream_t stream) {
    const float* level_tab    = (const float*)d_in[0];
    const float* type_tab     = (const float*)d_in[1];
    const float* feature_tab  = (const float*)d_in[2];
    const float* exchange_tab = (const float*)d_in[3];
    const float* pair_tab     = (const float*)d_in[4];
    const float* W            = (const float*)d_in[5];
    const float* b            = (const float*)d_in[6];
    const int*   li           = (const int*)d_in[7];
    const int*   ti           = (const int*)d_in[8];
    const int*   fi           = (const int*)d_in[9];
    const int*   ei           = (const int*)d_in[10];
    const int*   pi           = (const int*)d_in[11];

    float* out = (float*)d_out;
    float* C   = (float*)d_ws;          // 82*128*4 = 41984 bytes of scratch

    const int N = in_sizes[7];          // 1048576

    precompute_C<<<CROWS, EMBED, 0, stream>>>(
        level_tab, type_tab, feature_tab, exchange_tab, pair_tab, W, b, C);

    const int blocks = 2048;
    gather_add<<<blocks, 512, 0, stream>>>(li, ti, fi, ei, pi, C, out, N / 4);
}